// Round 8
// baseline (977.337 us; speedup 1.0000x reference)
//
#include <hip/hip_runtime.h>
#include <math.h>

#define NN 100000
#define NE 3200000
#define NG 512
#define NBK 782            // dst buckets: ceil(NN/128), bucket = dst>>7
#define EBLK 196           // edge super-blocks: ceil(NE/16384)
#define SBE 16384          // edges per super-block
#define STSH 13            // src-tile shift: 8192-node tiles (1MB of a 128B/row slice)
#define NTIL 13            // ceil(NN / 8192)
#define HB 196             // pre_k: hist blocks
#define WB 192             // pre_k: wswz blocks (6 cfgs x 32)
#define QB 12500           // pre_k: f2q blocks (NN*128/4 / 256)

typedef __attribute__((ext_vector_type(8))) short short8;
typedef __attribute__((ext_vector_type(4))) float f32x4;
typedef __attribute__((ext_vector_type(2))) float f32x2;

// ---------------- bf16 / fp8 helpers ----------------
__device__ __forceinline__ float bf2f(unsigned short h){
  return __uint_as_float(((unsigned int)h) << 16);
}
__device__ __forceinline__ unsigned short f2bf(float f){
  unsigned int u = __float_as_uint(f);
  unsigned int r = (u + 0x7fffu + ((u >> 16) & 1u)) >> 16;   // RNE
  return (unsigned short)r;
}
__device__ __forceinline__ unsigned char f2fp8(float v){
  int p = __builtin_amdgcn_cvt_pk_fp8_f32(v, v, 0, 0);
  return (unsigned char)p;
}

// ---------------- fused pre-pass: hist + weight swizzle + x->fp8 (one launch) ----------
__global__ __launch_bounds__(256) void pre_k(const int* __restrict__ ei,
    int* __restrict__ cnt, int* __restrict__ btot,
    const float* __restrict__ x, unsigned char* __restrict__ xq,
    const float* W1, const float* W2, const float* W3,
    const float* W4, const float* W5, const float* W6,
    unsigned short* O1, unsigned short* O2, unsigned short* O3,
    unsigned short* O4, unsigned short* O5, unsigned short* O6)
{
  __shared__ int lh[NBK];
  int b = blockIdx.x, t = threadIdx.x;
  if (b < HB){
    for (int i=t; i<NBK; i+=256) lh[i] = 0;
    __syncthreads();
    int base = b*SBE;
    #pragma unroll 8
    for (int u=0; u<SBE/256; u++){
      int e = base + u*256 + t;
      if (e < NE) atomicAdd(&lh[ei[NE + e] >> 7], 1);
    }
    __syncthreads();
    for (int i=t; i<NBK; i+=256){
      int v = lh[i];
      cnt[b*NBK + i] = v;
      if (v) atomicAdd(&btot[i], v);
    }
    return;
  }
  if (b < HB + WB){
    int bb = b - HB;
    int cfg = bb >> 5, bx = bb & 31;
    int K, N; const float* W; unsigned short* out;
    switch(cfg){
      case 0: K=128; N=256; W=W1; out=O1; break;
      case 1: K=256; N=256; W=W2; out=O2; break;
      case 2: K=256; N=256; W=W3; out=O3; break;
      case 3: K=256; N=128; W=W4; out=O4; break;
      case 4: K=128; N=128; W=W5; out=O5; break;
      default:K=128; N=64;  W=W6; out=O6; break;
    }
    int idx = bx*256 + t;
    int total = K*N/8;
    if (idx >= total) return;
    int l = idx & 15;
    int tt = idx >> 4; int q = tt & 3; tt >>= 2;
    int NT = N/16;
    int nt = tt % NT, kt = tt / NT;
    int kbase = kt*32 + q*8, n = nt*16 + l;
    short8 o;
    #pragma unroll
    for (int j=0;j<8;j++) o[j] = (short)f2bf(W[(size_t)(kbase+j)*N + n]);
    *(short8*)(out + (size_t)idx*8) = o;
    return;
  }
  {
    int i = (b - HB - WB)*256 + t;      // QB*256 == NN*128/4 exactly
    float4 v = ((const float4*)x)[i];
    int p = __builtin_amdgcn_cvt_pk_fp8_f32(v.x, v.y, 0, 0);
    p = __builtin_amdgcn_cvt_pk_fp8_f32(v.z, v.w, p, 1);
    ((unsigned int*)xq)[i] = (unsigned int)p;
  }
}

// per-bucket scan, with the 782-wide bucket-base prefix fused in.
__global__ __launch_bounds__(256) void bkpfx_k(int* __restrict__ cnt,
    const int* __restrict__ btot, int* __restrict__ bptr){
  __shared__ int sc[256];
  int b = blockIdx.x, t = threadIdx.x;
  int p = 0;
  for (int i = t; i < b; i += 256) p += btot[i];
  sc[t] = p; __syncthreads();
  for (int off=128; off>0; off>>=1){
    if (t < off) sc[t] += sc[t+off];
    __syncthreads();
  }
  int pb = sc[0];
  __syncthreads();
  if (t == 0){
    bptr[b] = pb;
    if (b == NBK-1) bptr[NBK] = pb + btot[b];
  }
  int v = (t < EBLK) ? cnt[t*NBK + b] : 0;
  sc[t] = v; __syncthreads();
  for (int off=1; off<256; off<<=1){
    int u = (t>=off) ? sc[t-off] : 0;
    __syncthreads(); sc[t] += u; __syncthreads();
  }
  if (t < EBLK) cnt[t*NBK + b] = pb + sc[t] - v;   // exclusive + base
}
__global__ __launch_bounds__(256) void scat2_k(const int* __restrict__ ei,
    const int* __restrict__ cnt, unsigned int* __restrict__ ebuf){
  __shared__ int lh[NBK];
  __shared__ int lo[NBK];
  int t = threadIdx.x, b = blockIdx.x;
  for (int i=t; i<NBK; i+=256){ lh[i] = 0; lo[i] = cnt[b*NBK + i]; }
  __syncthreads();
  int base = b*SBE;
  #pragma unroll 8
  for (int u=0; u<SBE/256; u++){
    int e = base + u*256 + t;
    if (e < NE){
      int s = ei[e], d = ei[NE + e];
      int bk = d >> 7;
      int r = atomicAdd(&lh[bk], 1);
      ebuf[lo[bk] + r] = (unsigned)s | ((unsigned)(d & 127) << 17);
    }
  }
}
// fused per-bucket CSR finalize: per-(row,tile) count + scan -> rp/dinv/col, 2 passes
// over ebuf total. col layout is src-tile-grouped per row. Emits degree-sorted perm.
__global__ __launch_bounds__(256) void bcsr_k(const unsigned int* __restrict__ ebuf,
    const int* __restrict__ bptr, int* __restrict__ rp, float* __restrict__ dinv,
    int* __restrict__ col, int* __restrict__ permg){
  __shared__ int cnt2[128*NTIL];   // per (li,tile) counts -> absolute running offsets
  __shared__ int sc[128];
  __shared__ int dg[128];
  int b = blockIdx.x, t = threadIdx.x;
  int nbase = b << 7;
  int beg = bptr[b], end = bptr[b+1];
  for (int i = t; i < 128*NTIL; i += 256) cnt2[i] = 0;
  __syncthreads();
  for (int e = beg + t; e < end; e += 256){
    unsigned int sd = ebuf[e];
    int li = sd >> 17;
    int tile = (int)(sd & 0x1FFFFu) >> STSH;
    atomicAdd(&cnt2[li*NTIL + tile], 1);
  }
  __syncthreads();
  int v = 0;
  if (t < 128){
    #pragma unroll
    for (int k=0;k<NTIL;k++) v += cnt2[t*NTIL+k];
    sc[t] = v;
    dg[t] = ((nbase + t) < NN) ? v : 0x7FFFFFFF;   // invalid slots sort to bucket end
  }
  __syncthreads();
  for (int o2=1; o2<128; o2<<=1){
    int u = (t < 128 && t >= o2) ? sc[t-o2] : 0;
    __syncthreads();
    if (t < 128) sc[t] += u;
    __syncthreads();
  }
  if (t < 128){
    int node = nbase + t;
    int ex = beg + sc[t] - v;          // exclusive row start
    if (node < NN){
      rp[node] = ex;
      dinv[node] = rsqrtf((float)(v + 1));
    }
    int s = ex;
    #pragma unroll
    for (int k=0;k<NTIL;k++){
      int c = cnt2[t*NTIL+k];
      cnt2[t*NTIL+k] = s;
      s += c;
    }
    int d = dg[t];
    int rk = 0;
    #pragma unroll 4
    for (int u2=0; u2<128; u2++){
      int du = dg[u2];
      rk += (int)((du < d) || (du == d && u2 < t));
    }
    permg[nbase + rk] = node;    // node >= NN for pad slots; spmm guards row>=NN
  }
  if (b == ((NN-1) >> 7) && t == 0) rp[NN] = end;
  __syncthreads();
  for (int e = beg + t; e < end; e += 256){
    unsigned int sd = ebuf[e];
    int li = sd >> 17;
    int src = (int)(sd & 0x1FFFF);
    int tile = src >> STSH;
    int pos = atomicAdd(&cnt2[li*NTIL + tile], 1);
    col[pos] = src;
  }
}

// ---------------- fp8 SpMM (packed-pair FMA + LPT wave scheduling) ----------------
// NOTE (R1-R6 evidence): pinned at ~3.6-3.7 TB/s random-gather ceiling. Do not touch.
template<int RS, int W, bool SRC_SCALE, bool RELU, bool HAS_BIAS>
__global__ __launch_bounds__(256) void spmm8_k(const unsigned char* __restrict__ in,
    unsigned short* __restrict__ out,
    const int* __restrict__ rp, const int* __restrict__ col,
    const float* __restrict__ dinv, const int* __restrict__ perm,
    const float* __restrict__ bias)
{
  constexpr int LPR = W/16;         // lanes per row
  constexpr int RPW = 64/LPR;       // rows per wave
  constexpr int GP  = 128/RPW;      // rank-groups per bucket
  int tid = threadIdx.x;
  int wv = tid >> 6, lane = tid & 63;
  int sub = lane / LPR, li = lane % LPR;
  int G = blockIdx.x*4 + wv;        // wave linear id over NBK*GP groups
  int bucket = G % NBK;
  int rg = (GP-1) - (G / NBK);      // descending degree: LPT
  int row = perm[(bucket << 7) + rg*RPW + sub];
  if (row >= NN) return;
  int beg = rp[row], end = rp[row+1];
  float di = dinv[row];
  int co = blockIdx.y*W + li*16;
  const unsigned char* inb = in + co;
  f32x2 acc2[8];
  {
    uint4 sv = *(const uint4*)(inb + (size_t)row*RS);   // self loop
    acc2[0] = __builtin_amdgcn_cvt_pk_f32_fp8(sv.x, 0);
    acc2[1] = __builtin_amdgcn_cvt_pk_f32_fp8(sv.x, 1);
    acc2[2] = __builtin_amdgcn_cvt_pk_f32_fp8(sv.y, 0);
    acc2[3] = __builtin_amdgcn_cvt_pk_f32_fp8(sv.y, 1);
    acc2[4] = __builtin_amdgcn_cvt_pk_f32_fp8(sv.z, 0);
    acc2[5] = __builtin_amdgcn_cvt_pk_f32_fp8(sv.z, 1);
    acc2[6] = __builtin_amdgcn_cvt_pk_f32_fp8(sv.w, 0);
    acc2[7] = __builtin_amdgcn_cvt_pk_f32_fp8(sv.w, 1);
    if (SRC_SCALE){
      f32x2 d2 = (f32x2){di, di};
      #pragma unroll
      for (int k=0;k<8;k++) acc2[k] = acc2[k] * d2;
    }
  }
  int j = beg;
  for (; j+8 <= end; j += 8){
    int s[8]; uint4 v[8]; float wgt[8];
    #pragma unroll
    for (int u=0;u<8;u++) s[u] = col[j+u];
    #pragma unroll
    for (int u=0;u<8;u++) v[u] = *(const uint4*)(inb + (size_t)s[u]*RS);
    if (SRC_SCALE){
      #pragma unroll
      for (int u=0;u<8;u++) wgt[u] = dinv[s[u]];
    }
    #pragma unroll
    for (int u=0;u<8;u++){
      float w = SRC_SCALE ? wgt[u] : 1.f;
      f32x2 w2 = (f32x2){w, w};
      acc2[0] = __builtin_elementwise_fma(w2, __builtin_amdgcn_cvt_pk_f32_fp8(v[u].x, 0), acc2[0]);
      acc2[1] = __builtin_elementwise_fma(w2, __builtin_amdgcn_cvt_pk_f32_fp8(v[u].x, 1), acc2[1]);
      acc2[2] = __builtin_elementwise_fma(w2, __builtin_amdgcn_cvt_pk_f32_fp8(v[u].y, 0), acc2[2]);
      acc2[3] = __builtin_elementwise_fma(w2, __builtin_amdgcn_cvt_pk_f32_fp8(v[u].y, 1), acc2[3]);
      acc2[4] = __builtin_elementwise_fma(w2, __builtin_amdgcn_cvt_pk_f32_fp8(v[u].z, 0), acc2[4]);
      acc2[5] = __builtin_elementwise_fma(w2, __builtin_amdgcn_cvt_pk_f32_fp8(v[u].z, 1), acc2[5]);
      acc2[6] = __builtin_elementwise_fma(w2, __builtin_amdgcn_cvt_pk_f32_fp8(v[u].w, 0), acc2[6]);
      acc2[7] = __builtin_elementwise_fma(w2, __builtin_amdgcn_cvt_pk_f32_fp8(v[u].w, 1), acc2[7]);
    }
  }
  for (; j < end; j++){
    int ss = col[j];
    uint4 v = *(const uint4*)(inb + (size_t)ss*RS);
    float w = SRC_SCALE ? dinv[ss] : 1.f;
    f32x2 w2 = (f32x2){w, w};
    acc2[0] = __builtin_elementwise_fma(w2, __builtin_amdgcn_cvt_pk_f32_fp8(v.x, 0), acc2[0]);
    acc2[1] = __builtin_elementwise_fma(w2, __builtin_amdgcn_cvt_pk_f32_fp8(v.x, 1), acc2[1]);
    acc2[2] = __builtin_elementwise_fma(w2, __builtin_amdgcn_cvt_pk_f32_fp8(v.y, 0), acc2[2]);
    acc2[3] = __builtin_elementwise_fma(w2, __builtin_amdgcn_cvt_pk_f32_fp8(v.y, 1), acc2[3]);
    acc2[4] = __builtin_elementwise_fma(w2, __builtin_amdgcn_cvt_pk_f32_fp8(v.z, 0), acc2[4]);
    acc2[5] = __builtin_elementwise_fma(w2, __builtin_amdgcn_cvt_pk_f32_fp8(v.z, 1), acc2[5]);
    acc2[6] = __builtin_elementwise_fma(w2, __builtin_amdgcn_cvt_pk_f32_fp8(v.w, 0), acc2[6]);
    acc2[7] = __builtin_elementwise_fma(w2, __builtin_amdgcn_cvt_pk_f32_fp8(v.w, 1), acc2[7]);
  }
  float acc[16];
  #pragma unroll
  for (int k=0;k<8;k++){ acc[2*k] = acc2[k][0]; acc[2*k+1] = acc2[k][1]; }
  float bb[16];
  if (HAS_BIAS){
    #pragma unroll
    for (int u=0;u<4;u++) *(float4*)&bb[u*4] = *(const float4*)(bias + co + u*4);
  }
  #pragma unroll
  for (int v=0;v<16;v++){
    acc[v] *= di;
    if (HAS_BIAS) acc[v] += bb[v];
    if (RELU) acc[v] = fmaxf(acc[v], 0.f);
  }
  uint4 o0, o1;
  o0.x = (unsigned int)f2bf(acc[0])  | ((unsigned int)f2bf(acc[1])<<16);
  o0.y = (unsigned int)f2bf(acc[2])  | ((unsigned int)f2bf(acc[3])<<16);
  o0.z = (unsigned int)f2bf(acc[4])  | ((unsigned int)f2bf(acc[5])<<16);
  o0.w = (unsigned int)f2bf(acc[6])  | ((unsigned int)f2bf(acc[7])<<16);
  o1.x = (unsigned int)f2bf(acc[8])  | ((unsigned int)f2bf(acc[9])<<16);
  o1.y = (unsigned int)f2bf(acc[10]) | ((unsigned int)f2bf(acc[11])<<16);
  o1.z = (unsigned int)f2bf(acc[12]) | ((unsigned int)f2bf(acc[13])<<16);
  o1.w = (unsigned int)f2bf(acc[14]) | ((unsigned int)f2bf(acc[15])<<16);
  unsigned short* op = out + (size_t)row*RS + co;
  *(uint4*)op = o0;
  *(uint4*)(op + 8) = o1;
}

// ---------------- MFMA bf16 GEMM, LDS-staged A (coalesced + XOR swizzle) ------------
// R7 analysis: the old per-thread A loads (16 lanes x 512B stride) split every load
// instruction into 16 transactions -> GEMMs ran ~5x below BW roofline. New design:
// block = 64 rows x 64 cols, 4 waves (wave w owns rows w*16..w*16+15).
// Stage: full 64 x K A-panel into LDS with PERFECTLY COALESCED row-contiguous loads
// (32 threads cover each 512B row), XOR-swizzled (byte ^= (row&7)<<4) so the
// fragment ds_read_b128 (16 lanes at 512B LDS stride) is 2-way-conflict (free, m136)
// instead of 16-way. One barrier, then pure-LDS K-loop: per kt 1 A + 4 B ds_reads,
// 4 MFMAs. Same fragment values & accumulation order as before -> bit-exact.
// XCD-aware 1D grid kept: all NSL col-slices of one row-panel land on one XCD's L2.
template<int K, int N, int EPI>
__global__ __launch_bounds__(256) void mgemm_k(const unsigned short* __restrict__ A,
    const unsigned short* __restrict__ Bsw,
    const float* __restrict__ aux, unsigned short* __restrict__ Cb,
    unsigned char* __restrict__ Cq, int M)
{
  constexpr int NT = 4;                   // 64 cols = 4 n-tiles
  constexpr int KT = K/32;
  constexpr int NTF = N/16;               // n-tiles in full Bsw
  constexpr int NSL = N/64;               // col-slices
  constexpr int SEGS = K/8;               // 16B segments per A row
  __shared__ short8 Bl[KT*NT*64];         // B 64-col slice: K*64*2 B
  __shared__ unsigned char Al[64*K*2];    // swizzled A panel: 64 rows x K bf16
  int tid = threadIdx.x;
  int w = tid >> 6, lane = tid & 63;
  int l = lane & 15, q = lane >> 4;
  int id = blockIdx.x;
  int xcd = id & 7, s = id >> 3;
  int xsl = s % NSL;
  int y = (s / NSL)*8 + xcd;
  int NYT = (M + 63)/64;
  if (y >= NYT) return;                   // uniform per block
  int nb0 = xsl * 64;                     // col slice
  int rb = y*64;                          // row panel
  // stage B slice
  {
    const short8* bsrc = (const short8*)Bsw;
    for (int i = tid; i < KT*NT*64; i += 256){
      int kt = i >> 8;
      int rem = i & 255;
      Bl[i] = bsrc[(kt*NTF + (nb0 >> 4))*64 + rem];
    }
  }
  // stage A panel, row-contiguous coalesced, XOR-swizzled
  for (int i = tid; i < 64*SEGS; i += 256){
    int row = i / SEGS, seg = i % SEGS;
    int gr = rb + row; if (gr >= M) gr = M-1;
    uint4 v = *(const uint4*)(A + (size_t)gr*K + seg*8);
    int sw = (seg*16) ^ ((row & 7) << 4);
    *(uint4*)(&Al[row*(K*2) + sw]) = v;
  }
  f32x4 acc[NT];
  #pragma unroll
  for (int nt=0; nt<NT; nt++) acc[nt] = (f32x4){0,0,0,0};
  __syncthreads();
  int rowl = w*16 + l;                    // local row 0..63
  int rbase = rowl*(K*2);
  int rxor = (rowl & 7) << 4;
  for (int kt=0; kt<KT; kt++){
    int kb = (kt*32 + q*8)*2;
    short8 af = *(const short8*)(&Al[rbase + (kb ^ rxor)]);
    const short8* bl = &Bl[kt << 8];
    #pragma unroll
    for (int nt=0; nt<NT; nt++){
      short8 bf = bl[nt*64 + q*16 + l];
      acc[nt] = __builtin_amdgcn_mfma_f32_16x16x32_bf16(af, bf, acc[nt], 0,0,0);
    }
  }
  int rbb = rb + w*16;
  #pragma unroll
  for (int nt=0; nt<NT; nt++){
    f32x4 av = acc[nt];
    int n = nb0 + nt*16 + l;
    #pragma unroll
    for (int r=0;r<4;r++){
      int row = rbb + q*4 + r;
      if (row < M){
        float v = av[r];
        if (EPI == 0){
          v = fmaxf(v + aux[n], 0.f);
          Cb[(size_t)row*N + n] = f2bf(v);
        } else {
          v *= aux[row];
          Cq[(size_t)row*N + n] = f2fp8(v);
        }
      }
    }
  }
}

// ---------------- fused mean-pool + linear + (log_)softmax (batch sorted) ----------------
__global__ __launch_bounds__(256) void poolhead_k(const unsigned short* __restrict__ h,
    const int* __restrict__ batch, const float* __restrict__ Wlin,
    const float* __restrict__ blin, float* __restrict__ out)
{
  __shared__ int range[2];
  __shared__ float red[4][64];
  __shared__ float pl[64];
  int g = blockIdx.x;
  if (threadIdx.x < 2){
    int target = g + threadIdx.x;      // lower_bound(batch, target)
    int lo = 0, hi = NN;
    while (lo < hi){ int m = (lo+hi) >> 1; if (batch[m] < target) lo = m+1; else hi = m; }
    range[threadIdx.x] = lo;
  }
  __syncthreads();
  int lo = range[0], hi = range[1];
  int ch = threadIdx.x & 63, rg = threadIdx.x >> 6;
  float s = 0.f;
  for (int r = lo + rg; r < hi; r += 4) s += bf2f(h[(size_t)r*64 + ch]);
  red[rg][ch] = s; __syncthreads();
  if (rg == 0){
    float tot = red[0][ch] + red[1][ch] + red[2][ch] + red[3][ch];
    pl[ch] = tot / fmaxf((float)(hi - lo), 1.f);
  }
  __syncthreads();
  if (threadIdx.x == 0){
    float l[10];
    #pragma unroll
    for (int j=0;j<10;j++) l[j] = blin[j];
    for (int c=0;c<64;c++){
      float p = pl[c];
      #pragma unroll
      for (int j=0;j<10;j++) l[j] = fmaf(p, Wlin[c*10 + j], l[j]);
    }
    float mx = l[0];
    #pragma unroll
    for (int j=1;j<10;j++) mx = fmaxf(mx, l[j]);
    float e[10]; float se = 0.f;
    #pragma unroll
    for (int j=0;j<10;j++){ e[j] = expf(l[j]-mx); se += e[j]; }
    float lse = logf(se);
    #pragma unroll
    for (int j=0;j<10;j++){
      out[g*10 + j]         = l[j] - mx - lse;   // log_softmax
      out[NG*10 + g*10 + j] = e[j] / se;         // softmax
    }
  }
}

// ---------------- launch ----------------
extern "C" void kernel_launch(void* const* d_in, const int* in_sizes, int n_in,
                              void* d_out, int out_size, void* d_ws, size_t ws_size,
                              hipStream_t stream)
{
  const float* x     = (const float*)d_in[0];
  const int*   ei    = (const int*)  d_in[1];
  const int*   batch = (const int*)  d_in[2];
  const float* W1=(const float*)d_in[4],  *b1=(const float*)d_in[5];
  const float* W2=(const float*)d_in[6],  *b2=(const float*)d_in[7];
  const float* W3=(const float*)d_in[8],  *b3=(const float*)d_in[9];
  const float* W4=(const float*)d_in[10], *b4=(const float*)d_in[11];
  const float* W5=(const float*)d_in[12], *b5=(const float*)d_in[13];
  const float* W6=(const float*)d_in[14], *b6=(const float*)d_in[15];
  const float* Wl=(const float*)d_in[16], *bl=(const float*)d_in[17];
  float* out = (float*)d_out;

  char* ws = (char*)d_ws;
  unsigned short* hA  = (unsigned short*)(ws + 0);            // bf16 51,200,000
  unsigned short* hB  = (unsigned short*)(ws + 51200000);     // bf16 51,200,000
  unsigned char*  hQ  = (unsigned char*) (ws + 102400000);    // fp8  25,600,000
  unsigned char*  xq  = (unsigned char*) (ws + 128000000);    // fp8  12,800,000
  int*   col   = (int*)  (ws + 140800000);                    // 12,800,000
  unsigned int* ebuf = (unsigned int*)(ws + 153600000);       // 12,800,000 (packed)
  int*   rp    = (int*)  (ws + 166400000);                    // 400,016
  float* dinv  = (float*)(ws + 166800016);                    // 400,000
  unsigned short* W1s = (unsigned short*)(ws + 167200016);    // 65,536
  unsigned short* W2s = (unsigned short*)(ws + 167265552);    // 131,072
  unsigned short* W3s = (unsigned short*)(ws + 167396624);    // 131,072
  unsigned short* W4s = (unsigned short*)(ws + 167527696);    // 65,536
  unsigned short* W5s = (unsigned short*)(ws + 167593232);    // 32,768
  unsigned short* W6s = (unsigned short*)(ws + 167626000);    // 16,384
  int*   btot  = (int*)  (ws + 167642896);                    // 3,128
  int*   bptr  = (int*)  (ws + 167646032);                    // 3,132
  int*   cnt   = (int*)  (ws + 167649184);                    // 196*782*4 = 613,088
  // perm overlaps cnt: cnt's last reader is scat2_k, bcsr_k (writer of perm) runs after.
  int*   perm  = cnt;                                         // NBK*128 = 100,096 ints

  hipMemsetAsync(btot, 0, NBK*4, stream);

  // fused pre-pass (hist + wswz + f2q), then scan-based multi-split CSR build
  pre_k <<<HB+WB+QB, 256, 0, stream>>>(ei, cnt, btot, x, xq,
      W1,W2,W3,W4,W5,W6, W1s,W2s,W3s,W4s,W5s,W6s);
  bkpfx_k <<<NBK, 256, 0, stream>>>(cnt, btot, bptr);
  scat2_k <<<EBLK, 256, 0, stream>>>(ei, cnt, ebuf);
  bcsr_k  <<<NBK, 256, 0, stream>>>(ebuf, bptr, rp, dinv, col, perm);

  const int GX128 = NBK*16/4;   // W=128: 16 wave-groups/bucket, 4 waves/block = 3128
  const int GX64  = NBK*8/4;    // W=64:   8 wave-groups/bucket -> 1564
  const int NYT   = (NN + 63)/64;      // gemm row-panels (1563)
  const int GY8   = (NYT + 7)/8;       // row-panels per XCD stripe (196)
  const int G256  = 8*4*GY8;           // N=256: 6272 blocks
  const int G128  = 8*2*GY8;           // N=128: 3136
  const int G64   = 8*1*GY8;           // N=64:  1568

  // L1: aggregate-first at width 128 (Â x, fp8 gather), then GEMM 128->256 (+b1, relu, bf16)
  spmm8_k<128,128,true,false,false><<<dim3(GX128,1),256,0,stream>>>(xq, hA, rp, col, dinv, perm, nullptr);
  mgemm_k<128,256,0><<<G256,256,0,stream>>>(hA, W1s, b1, hB, nullptr, NN);
  // L2: GEMM (*dinv -> fp8), spmm fp8 gather split into two 128-col slices (+b2, relu -> bf16)
  mgemm_k<256,256,1><<<G256,256,0,stream>>>(hB, W2s, dinv, nullptr, hQ, NN);
  spmm8_k<256,128,false,true,true><<<dim3(GX128,2),256,0,stream>>>(hQ, hA, rp, col, dinv, perm, b2);
  // L3
  mgemm_k<256,256,1><<<G256,256,0,stream>>>(hA, W3s, dinv, nullptr, hQ, NN);
  spmm8_k<256,128,false,true,true><<<dim3(GX128,2),256,0,stream>>>(hQ, hB, rp, col, dinv, perm, b3);
  // L4: 256->128
  mgemm_k<256,128,1><<<G128,256,0,stream>>>(hB, W4s, dinv, nullptr, hQ, NN);
  spmm8_k<128,128,false,true,true><<<dim3(GX128,1),256,0,stream>>>(hQ, hA, rp, col, dinv, perm, b4);
  // L5: 128->128
  mgemm_k<128,128,1><<<G128,256,0,stream>>>(hA, W5s, dinv, nullptr, hQ, NN);
  spmm8_k<128,128,false,true,true><<<dim3(GX128,1),256,0,stream>>>(hQ, hB, rp, col, dinv, perm, b5);
  // L6: 128->64, no relu
  mgemm_k<128,64,1><<<G64,256,0,stream>>>(hB, W6s, dinv, nullptr, hQ, NN);
  spmm8_k<64,64,false,false,true><<<dim3(GX64,1),256,0,stream>>>(hQ, hA, rp, col, dinv, perm, b6);

  // fused deterministic mean-pool + head
  poolhead_k<<<NG, 256, 0, stream>>>(hA, batch, Wl, bl, out);
}

// Round 9
// 957.095 us; speedup vs baseline: 1.0211x; 1.0211x over previous
//
#include <hip/hip_runtime.h>
#include <math.h>

#define NN 100000
#define NE 3200000
#define NG 512
#define NBK 782            // dst buckets: ceil(NN/128), bucket = dst>>7
#define EBLK 196           // edge super-blocks: ceil(NE/16384)
#define SBE 16384          // edges per super-block
#define STSH 13            // src-tile shift: 8192-node tiles (1MB of a 128B/row slice)
#define NTIL 13            // ceil(NN / 8192)
#define HB 196             // pre_k: hist blocks
#define WB 192             // pre_k: wswz blocks (6 cfgs x 32)
#define QB 12500           // pre_k: f2q blocks (NN*128/4 / 256)

typedef __attribute__((ext_vector_type(8))) short short8;
typedef __attribute__((ext_vector_type(4))) float f32x4;
typedef __attribute__((ext_vector_type(2))) float f32x2;

// ---------------- bf16 / fp8 helpers ----------------
__device__ __forceinline__ float bf2f(unsigned short h){
  return __uint_as_float(((unsigned int)h) << 16);
}
__device__ __forceinline__ unsigned short f2bf(float f){
  unsigned int u = __float_as_uint(f);
  unsigned int r = (u + 0x7fffu + ((u >> 16) & 1u)) >> 16;   // RNE
  return (unsigned short)r;
}
__device__ __forceinline__ unsigned char f2fp8(float v){
  int p = __builtin_amdgcn_cvt_pk_fp8_f32(v, v, 0, 0);
  return (unsigned char)p;
}

// ---------------- fused pre-pass: hist + weight swizzle + x->fp8 (one launch) ----------
__global__ __launch_bounds__(256) void pre_k(const int* __restrict__ ei,
    int* __restrict__ cnt, int* __restrict__ btot,
    const float* __restrict__ x, unsigned char* __restrict__ xq,
    const float* W1, const float* W2, const float* W3,
    const float* W4, const float* W5, const float* W6,
    unsigned short* O1, unsigned short* O2, unsigned short* O3,
    unsigned short* O4, unsigned short* O5, unsigned short* O6)
{
  __shared__ int lh[NBK];
  int b = blockIdx.x, t = threadIdx.x;
  if (b < HB){
    for (int i=t; i<NBK; i+=256) lh[i] = 0;
    __syncthreads();
    int base = b*SBE;
    #pragma unroll 8
    for (int u=0; u<SBE/256; u++){
      int e = base + u*256 + t;
      if (e < NE) atomicAdd(&lh[ei[NE + e] >> 7], 1);
    }
    __syncthreads();
    for (int i=t; i<NBK; i+=256){
      int v = lh[i];
      cnt[b*NBK + i] = v;
      if (v) atomicAdd(&btot[i], v);
    }
    return;
  }
  if (b < HB + WB){
    int bb = b - HB;
    int cfg = bb >> 5, bx = bb & 31;
    int K, N; const float* W; unsigned short* out;
    switch(cfg){
      case 0: K=128; N=256; W=W1; out=O1; break;
      case 1: K=256; N=256; W=W2; out=O2; break;
      case 2: K=256; N=256; W=W3; out=O3; break;
      case 3: K=256; N=128; W=W4; out=O4; break;
      case 4: K=128; N=128; W=W5; out=O5; break;
      default:K=128; N=64;  W=W6; out=O6; break;
    }
    int idx = bx*256 + t;
    int total = K*N/8;
    if (idx >= total) return;
    int l = idx & 15;
    int tt = idx >> 4; int q = tt & 3; tt >>= 2;
    int NT = N/16;
    int nt = tt % NT, kt = tt / NT;
    int kbase = kt*32 + q*8, n = nt*16 + l;
    short8 o;
    #pragma unroll
    for (int j=0;j<8;j++) o[j] = (short)f2bf(W[(size_t)(kbase+j)*N + n]);
    *(short8*)(out + (size_t)idx*8) = o;
    return;
  }
  {
    int i = (b - HB - WB)*256 + t;      // QB*256 == NN*128/4 exactly
    float4 v = ((const float4*)x)[i];
    int p = __builtin_amdgcn_cvt_pk_fp8_f32(v.x, v.y, 0, 0);
    p = __builtin_amdgcn_cvt_pk_fp8_f32(v.z, v.w, p, 1);
    ((unsigned int*)xq)[i] = (unsigned int)p;
  }
}

// per-bucket scan, with the 782-wide bucket-base prefix fused in.
__global__ __launch_bounds__(256) void bkpfx_k(int* __restrict__ cnt,
    const int* __restrict__ btot, int* __restrict__ bptr){
  __shared__ int sc[256];
  int b = blockIdx.x, t = threadIdx.x;
  int p = 0;
  for (int i = t; i < b; i += 256) p += btot[i];
  sc[t] = p; __syncthreads();
  for (int off=128; off>0; off>>=1){
    if (t < off) sc[t] += sc[t+off];
    __syncthreads();
  }
  int pb = sc[0];
  __syncthreads();
  if (t == 0){
    bptr[b] = pb;
    if (b == NBK-1) bptr[NBK] = pb + btot[b];
  }
  int v = (t < EBLK) ? cnt[t*NBK + b] : 0;
  sc[t] = v; __syncthreads();
  for (int off=1; off<256; off<<=1){
    int u = (t>=off) ? sc[t-off] : 0;
    __syncthreads(); sc[t] += u; __syncthreads();
  }
  if (t < EBLK) cnt[t*NBK + b] = pb + sc[t] - v;   // exclusive + base
}
__global__ __launch_bounds__(256) void scat2_k(const int* __restrict__ ei,
    const int* __restrict__ cnt, unsigned int* __restrict__ ebuf){
  __shared__ int lh[NBK];
  __shared__ int lo[NBK];
  int t = threadIdx.x, b = blockIdx.x;
  for (int i=t; i<NBK; i+=256){ lh[i] = 0; lo[i] = cnt[b*NBK + i]; }
  __syncthreads();
  int base = b*SBE;
  #pragma unroll 8
  for (int u=0; u<SBE/256; u++){
    int e = base + u*256 + t;
    if (e < NE){
      int s = ei[e], d = ei[NE + e];
      int bk = d >> 7;
      int r = atomicAdd(&lh[bk], 1);
      ebuf[lo[bk] + r] = (unsigned)s | ((unsigned)(d & 127) << 17);
    }
  }
}
// fused per-bucket CSR finalize: per-(row,tile) count + scan -> rp/dinv/col, 2 passes
// over ebuf total. col layout is src-tile-grouped per row. Emits degree-sorted perm.
__global__ __launch_bounds__(256) void bcsr_k(const unsigned int* __restrict__ ebuf,
    const int* __restrict__ bptr, int* __restrict__ rp, float* __restrict__ dinv,
    int* __restrict__ col, int* __restrict__ permg){
  __shared__ int cnt2[128*NTIL];   // per (li,tile) counts -> absolute running offsets
  __shared__ int sc[128];
  __shared__ int dg[128];
  int b = blockIdx.x, t = threadIdx.x;
  int nbase = b << 7;
  int beg = bptr[b], end = bptr[b+1];
  for (int i = t; i < 128*NTIL; i += 256) cnt2[i] = 0;
  __syncthreads();
  for (int e = beg + t; e < end; e += 256){
    unsigned int sd = ebuf[e];
    int li = sd >> 17;
    int tile = (int)(sd & 0x1FFFFu) >> STSH;
    atomicAdd(&cnt2[li*NTIL + tile], 1);
  }
  __syncthreads();
  int v = 0;
  if (t < 128){
    #pragma unroll
    for (int k=0;k<NTIL;k++) v += cnt2[t*NTIL+k];
    sc[t] = v;
    dg[t] = ((nbase + t) < NN) ? v : 0x7FFFFFFF;   // invalid slots sort to bucket end
  }
  __syncthreads();
  for (int o2=1; o2<128; o2<<=1){
    int u = (t < 128 && t >= o2) ? sc[t-o2] : 0;
    __syncthreads();
    if (t < 128) sc[t] += u;
    __syncthreads();
  }
  if (t < 128){
    int node = nbase + t;
    int ex = beg + sc[t] - v;          // exclusive row start
    if (node < NN){
      rp[node] = ex;
      dinv[node] = rsqrtf((float)(v + 1));
    }
    int s = ex;
    #pragma unroll
    for (int k=0;k<NTIL;k++){
      int c = cnt2[t*NTIL+k];
      cnt2[t*NTIL+k] = s;
      s += c;
    }
    int d = dg[t];
    int rk = 0;
    #pragma unroll 4
    for (int u2=0; u2<128; u2++){
      int du = dg[u2];
      rk += (int)((du < d) || (du == d && u2 < t));
    }
    permg[nbase + rk] = node;    // node >= NN for pad slots; spmm guards row>=NN
  }
  if (b == ((NN-1) >> 7) && t == 0) rp[NN] = end;
  __syncthreads();
  for (int e = beg + t; e < end; e += 256){
    unsigned int sd = ebuf[e];
    int li = sd >> 17;
    int src = (int)(sd & 0x1FFFF);
    int tile = src >> STSH;
    int pos = atomicAdd(&cnt2[li*NTIL + tile], 1);
    col[pos] = src;
  }
}

// ---------------- fp8 SpMM (packed-pair FMA + LPT wave scheduling) ----------------
// NOTE (R1-R8 evidence): pinned at ~3.6-3.7 TB/s random-gather ceiling. Do not touch.
template<int RS, int W, bool SRC_SCALE, bool RELU, bool HAS_BIAS>
__global__ __launch_bounds__(256) void spmm8_k(const unsigned char* __restrict__ in,
    unsigned short* __restrict__ out,
    const int* __restrict__ rp, const int* __restrict__ col,
    const float* __restrict__ dinv, const int* __restrict__ perm,
    const float* __restrict__ bias)
{
  constexpr int LPR = W/16;         // lanes per row
  constexpr int RPW = 64/LPR;       // rows per wave
  constexpr int GP  = 128/RPW;      // rank-groups per bucket
  int tid = threadIdx.x;
  int wv = tid >> 6, lane = tid & 63;
  int sub = lane / LPR, li = lane % LPR;
  int G = blockIdx.x*4 + wv;        // wave linear id over NBK*GP groups
  int bucket = G % NBK;
  int rg = (GP-1) - (G / NBK);      // descending degree: LPT
  int row = perm[(bucket << 7) + rg*RPW + sub];
  if (row >= NN) return;
  int beg = rp[row], end = rp[row+1];
  float di = dinv[row];
  int co = blockIdx.y*W + li*16;
  const unsigned char* inb = in + co;
  f32x2 acc2[8];
  {
    uint4 sv = *(const uint4*)(inb + (size_t)row*RS);   // self loop
    acc2[0] = __builtin_amdgcn_cvt_pk_f32_fp8(sv.x, 0);
    acc2[1] = __builtin_amdgcn_cvt_pk_f32_fp8(sv.x, 1);
    acc2[2] = __builtin_amdgcn_cvt_pk_f32_fp8(sv.y, 0);
    acc2[3] = __builtin_amdgcn_cvt_pk_f32_fp8(sv.y, 1);
    acc2[4] = __builtin_amdgcn_cvt_pk_f32_fp8(sv.z, 0);
    acc2[5] = __builtin_amdgcn_cvt_pk_f32_fp8(sv.z, 1);
    acc2[6] = __builtin_amdgcn_cvt_pk_f32_fp8(sv.w, 0);
    acc2[7] = __builtin_amdgcn_cvt_pk_f32_fp8(sv.w, 1);
    if (SRC_SCALE){
      f32x2 d2 = (f32x2){di, di};
      #pragma unroll
      for (int k=0;k<8;k++) acc2[k] = acc2[k] * d2;
    }
  }
  int j = beg;
  for (; j+8 <= end; j += 8){
    int s[8]; uint4 v[8]; float wgt[8];
    #pragma unroll
    for (int u=0;u<8;u++) s[u] = col[j+u];
    #pragma unroll
    for (int u=0;u<8;u++) v[u] = *(const uint4*)(inb + (size_t)s[u]*RS);
    if (SRC_SCALE){
      #pragma unroll
      for (int u=0;u<8;u++) wgt[u] = dinv[s[u]];
    }
    #pragma unroll
    for (int u=0;u<8;u++){
      float w = SRC_SCALE ? wgt[u] : 1.f;
      f32x2 w2 = (f32x2){w, w};
      acc2[0] = __builtin_elementwise_fma(w2, __builtin_amdgcn_cvt_pk_f32_fp8(v[u].x, 0), acc2[0]);
      acc2[1] = __builtin_elementwise_fma(w2, __builtin_amdgcn_cvt_pk_f32_fp8(v[u].x, 1), acc2[1]);
      acc2[2] = __builtin_elementwise_fma(w2, __builtin_amdgcn_cvt_pk_f32_fp8(v[u].y, 0), acc2[2]);
      acc2[3] = __builtin_elementwise_fma(w2, __builtin_amdgcn_cvt_pk_f32_fp8(v[u].y, 1), acc2[3]);
      acc2[4] = __builtin_elementwise_fma(w2, __builtin_amdgcn_cvt_pk_f32_fp8(v[u].z, 0), acc2[4]);
      acc2[5] = __builtin_elementwise_fma(w2, __builtin_amdgcn_cvt_pk_f32_fp8(v[u].z, 1), acc2[5]);
      acc2[6] = __builtin_elementwise_fma(w2, __builtin_amdgcn_cvt_pk_f32_fp8(v[u].w, 0), acc2[6]);
      acc2[7] = __builtin_elementwise_fma(w2, __builtin_amdgcn_cvt_pk_f32_fp8(v[u].w, 1), acc2[7]);
    }
  }
  for (; j < end; j++){
    int ss = col[j];
    uint4 v = *(const uint4*)(inb + (size_t)ss*RS);
    float w = SRC_SCALE ? dinv[ss] : 1.f;
    f32x2 w2 = (f32x2){w, w};
    acc2[0] = __builtin_elementwise_fma(w2, __builtin_amdgcn_cvt_pk_f32_fp8(v.x, 0), acc2[0]);
    acc2[1] = __builtin_elementwise_fma(w2, __builtin_amdgcn_cvt_pk_f32_fp8(v.x, 1), acc2[1]);
    acc2[2] = __builtin_elementwise_fma(w2, __builtin_amdgcn_cvt_pk_f32_fp8(v.y, 0), acc2[2]);
    acc2[3] = __builtin_elementwise_fma(w2, __builtin_amdgcn_cvt_pk_f32_fp8(v.y, 1), acc2[3]);
    acc2[4] = __builtin_elementwise_fma(w2, __builtin_amdgcn_cvt_pk_f32_fp8(v.z, 0), acc2[4]);
    acc2[5] = __builtin_elementwise_fma(w2, __builtin_amdgcn_cvt_pk_f32_fp8(v.z, 1), acc2[5]);
    acc2[6] = __builtin_elementwise_fma(w2, __builtin_amdgcn_cvt_pk_f32_fp8(v.w, 0), acc2[6]);
    acc2[7] = __builtin_elementwise_fma(w2, __builtin_amdgcn_cvt_pk_f32_fp8(v.w, 1), acc2[7]);
  }
  float acc[16];
  #pragma unroll
  for (int k=0;k<8;k++){ acc[2*k] = acc2[k][0]; acc[2*k+1] = acc2[k][1]; }
  float bb[16];
  if (HAS_BIAS){
    #pragma unroll
    for (int u=0;u<4;u++) *(float4*)&bb[u*4] = *(const float4*)(bias + co + u*4);
  }
  #pragma unroll
  for (int v=0;v<16;v++){
    acc[v] *= di;
    if (HAS_BIAS) acc[v] += bb[v];
    if (RELU) acc[v] = fmaxf(acc[v], 0.f);
  }
  uint4 o0, o1;
  o0.x = (unsigned int)f2bf(acc[0])  | ((unsigned int)f2bf(acc[1])<<16);
  o0.y = (unsigned int)f2bf(acc[2])  | ((unsigned int)f2bf(acc[3])<<16);
  o0.z = (unsigned int)f2bf(acc[4])  | ((unsigned int)f2bf(acc[5])<<16);
  o0.w = (unsigned int)f2bf(acc[6])  | ((unsigned int)f2bf(acc[7])<<16);
  o1.x = (unsigned int)f2bf(acc[8])  | ((unsigned int)f2bf(acc[9])<<16);
  o1.y = (unsigned int)f2bf(acc[10]) | ((unsigned int)f2bf(acc[11])<<16);
  o1.z = (unsigned int)f2bf(acc[12]) | ((unsigned int)f2bf(acc[13])<<16);
  o1.w = (unsigned int)f2bf(acc[14]) | ((unsigned int)f2bf(acc[15])<<16);
  unsigned short* op = out + (size_t)row*RS + co;
  *(uint4*)op = o0;
  *(uint4*)(op + 8) = o1;
}

// ---------------- MFMA bf16 GEMM: 128x64 tile, BK=64 double-buffered LDS A -----------
// R8 post-mortem: 64x64 tile fixed A-coalescing but 4x'd B re-staging; R7 had good B
// amortization but 16-way-split A transactions. This combines the fixes:
//  - B slice (Kx64, <=32KB) staged ONCE per block (R7 style, conflict-free reads).
//  - A staged per 64-col K-step into a 16KB double buffer: each wave instruction loads
//    8 rows x 128B FULL LINES (perfect coalescing), reg->ds_write with XOR swizzle
//    (byte ^= (row&7)<<4) so fragment ds_read_b128 spreads 16 lanes over 32 banks
//    (2 lanes/bank = free, m136). One barrier per K-step; stage(ks+1) overlaps compute.
//  - kt-ascending MFMA order per acc element identical to R7 -> bit-exact.
// LDS: 32KB(B,K=256) + 2x16KB(A) = 64KB -> 2 blocks/CU, 8 waves/CU.
// XCD-aware 1D grid: all NSL col-slices of one row-panel land on one XCD's L2.
template<int K, int N, int EPI>
__global__ __launch_bounds__(256) void mgemm_k(const unsigned short* __restrict__ A,
    const unsigned short* __restrict__ Bsw,
    const float* __restrict__ aux, unsigned short* __restrict__ Cb,
    unsigned char* __restrict__ Cq, int M)
{
  constexpr int NT = 4;                   // 64 cols = 4 n-tiles
  constexpr int KT = K/32;
  constexpr int NTF = N/16;               // n-tiles in full Bsw
  constexpr int NSL = N/64;               // col-slices
  constexpr int NKS = K/64;               // 64-col K-steps
  __shared__ short8 Bl[KT*NT*64];         // B 64-col slice: K*128 B
  __shared__ unsigned char Al[2][128*128];// A dbuf: 128 rows x 128B, XOR-swizzled
  int tid = threadIdx.x;
  int w = tid >> 6, lane = tid & 63;
  int l = lane & 15, q = lane >> 4;
  int id = blockIdx.x;
  int xcd = id & 7, s = id >> 3;
  int xsl = s % NSL;
  int y = (s / NSL)*8 + xcd;
  int NYT = (M + 127)/128;
  if (y >= NYT) return;                   // uniform per block
  int nb0 = xsl * 64;                     // col slice
  int rb = y*128;                         // row panel
  // stage B slice (once)
  {
    const short8* bsrc = (const short8*)Bsw;
    for (int i = tid; i < KT*NT*64; i += 256){
      int kt = i >> 8;
      int rem = i & 255;
      Bl[i] = bsrc[(kt*NTF + (nb0 >> 4))*64 + rem];
    }
  }
  // prologue: stage A k-step 0 into buf 0 (coalesced full lines, swizzled ds_write)
  #pragma unroll
  for (int it = 0; it < 4; it++){
    int i = it*256 + tid;                 // 1024 chunks = 128 rows x 8
    int row = i >> 3, ch = i & 7;
    int gr = rb + row; if (gr >= M) gr = M-1;
    uint4 v = *(const uint4*)(A + (size_t)gr*K + ch*8);
    *(uint4*)(&Al[0][row*128 + ((ch*16) ^ ((row & 7) << 4))]) = v;
  }
  f32x4 acc[2][NT];
  #pragma unroll
  for (int rt=0; rt<2; rt++)
    #pragma unroll
    for (int nt=0; nt<NT; nt++) acc[rt][nt] = (f32x4){0,0,0,0};
  __syncthreads();
  int buf = 0;
  for (int ks=0; ks<NKS; ks++){
    if (ks+1 < NKS){                      // stage next k-step into other buffer
      #pragma unroll
      for (int it = 0; it < 4; it++){
        int i = it*256 + tid;
        int row = i >> 3, ch = i & 7;
        int gr = rb + row; if (gr >= M) gr = M-1;
        uint4 v = *(const uint4*)(A + (size_t)gr*K + (ks+1)*64 + ch*8);
        *(uint4*)(&Al[buf^1][row*128 + ((ch*16) ^ ((row & 7) << 4))]) = v;
      }
    }
    #pragma unroll
    for (int kk=0; kk<2; kk++){
      int kt = ks*2 + kk;
      const short8* bl = &Bl[kt << 8];
      short8 af[2];
      #pragma unroll
      for (int rt=0; rt<2; rt++){
        int row = w*32 + rt*16 + l;
        af[rt] = *(const short8*)(&Al[buf][row*128 + ((kk*64 + q*16) ^ ((row & 7) << 4))]);
      }
      #pragma unroll
      for (int nt=0; nt<NT; nt++){
        short8 bf = bl[nt*64 + q*16 + l];
        acc[0][nt] = __builtin_amdgcn_mfma_f32_16x16x32_bf16(af[0], bf, acc[0][nt], 0,0,0);
        acc[1][nt] = __builtin_amdgcn_mfma_f32_16x16x32_bf16(af[1], bf, acc[1][nt], 0,0,0);
      }
    }
    __syncthreads();
    buf ^= 1;
  }
  #pragma unroll
  for (int rt=0; rt<2; rt++){
    int rbb = rb + w*32 + rt*16;
    #pragma unroll
    for (int nt=0; nt<NT; nt++){
      f32x4 av = acc[rt][nt];
      int n = nb0 + nt*16 + l;
      #pragma unroll
      for (int r=0;r<4;r++){
        int row = rbb + q*4 + r;
        if (row < M){
          float v = av[r];
          if (EPI == 0){
            v = fmaxf(v + aux[n], 0.f);
            Cb[(size_t)row*N + n] = f2bf(v);
          } else {
            v *= aux[row];
            Cq[(size_t)row*N + n] = f2fp8(v);
          }
        }
      }
    }
  }
}

// ---------------- fused mean-pool + linear + (log_)softmax (batch sorted) ----------------
__global__ __launch_bounds__(256) void poolhead_k(const unsigned short* __restrict__ h,
    const int* __restrict__ batch, const float* __restrict__ Wlin,
    const float* __restrict__ blin, float* __restrict__ out)
{
  __shared__ int range[2];
  __shared__ float red[4][64];
  __shared__ float pl[64];
  int g = blockIdx.x;
  if (threadIdx.x < 2){
    int target = g + threadIdx.x;      // lower_bound(batch, target)
    int lo = 0, hi = NN;
    while (lo < hi){ int m = (lo+hi) >> 1; if (batch[m] < target) lo = m+1; else hi = m; }
    range[threadIdx.x] = lo;
  }
  __syncthreads();
  int lo = range[0], hi = range[1];
  int ch = threadIdx.x & 63, rg = threadIdx.x >> 6;
  float s = 0.f;
  for (int r = lo + rg; r < hi; r += 4) s += bf2f(h[(size_t)r*64 + ch]);
  red[rg][ch] = s; __syncthreads();
  if (rg == 0){
    float tot = red[0][ch] + red[1][ch] + red[2][ch] + red[3][ch];
    pl[ch] = tot / fmaxf((float)(hi - lo), 1.f);
  }
  __syncthreads();
  if (threadIdx.x == 0){
    float l[10];
    #pragma unroll
    for (int j=0;j<10;j++) l[j] = blin[j];
    for (int c=0;c<64;c++){
      float p = pl[c];
      #pragma unroll
      for (int j=0;j<10;j++) l[j] = fmaf(p, Wlin[c*10 + j], l[j]);
    }
    float mx = l[0];
    #pragma unroll
    for (int j=1;j<10;j++) mx = fmaxf(mx, l[j]);
    float e[10]; float se = 0.f;
    #pragma unroll
    for (int j=0;j<10;j++){ e[j] = expf(l[j]-mx); se += e[j]; }
    float lse = logf(se);
    #pragma unroll
    for (int j=0;j<10;j++){
      out[g*10 + j]         = l[j] - mx - lse;   // log_softmax
      out[NG*10 + g*10 + j] = e[j] / se;         // softmax
    }
  }
}

// ---------------- launch ----------------
extern "C" void kernel_launch(void* const* d_in, const int* in_sizes, int n_in,
                              void* d_out, int out_size, void* d_ws, size_t ws_size,
                              hipStream_t stream)
{
  const float* x     = (const float*)d_in[0];
  const int*   ei    = (const int*)  d_in[1];
  const int*   batch = (const int*)  d_in[2];
  const float* W1=(const float*)d_in[4],  *b1=(const float*)d_in[5];
  const float* W2=(const float*)d_in[6],  *b2=(const float*)d_in[7];
  const float* W3=(const float*)d_in[8],  *b3=(const float*)d_in[9];
  const float* W4=(const float*)d_in[10], *b4=(const float*)d_in[11];
  const float* W5=(const float*)d_in[12], *b5=(const float*)d_in[13];
  const float* W6=(const float*)d_in[14], *b6=(const float*)d_in[15];
  const float* Wl=(const float*)d_in[16], *bl=(const float*)d_in[17];
  float* out = (float*)d_out;

  char* ws = (char*)d_ws;
  unsigned short* hA  = (unsigned short*)(ws + 0);            // bf16 51,200,000
  unsigned short* hB  = (unsigned short*)(ws + 51200000);     // bf16 51,200,000
  unsigned char*  hQ  = (unsigned char*) (ws + 102400000);    // fp8  25,600,000
  unsigned char*  xq  = (unsigned char*) (ws + 128000000);    // fp8  12,800,000
  int*   col   = (int*)  (ws + 140800000);                    // 12,800,000
  unsigned int* ebuf = (unsigned int*)(ws + 153600000);       // 12,800,000 (packed)
  int*   rp    = (int*)  (ws + 166400000);                    // 400,016
  float* dinv  = (float*)(ws + 166800016);                    // 400,000
  unsigned short* W1s = (unsigned short*)(ws + 167200016);    // 65,536
  unsigned short* W2s = (unsigned short*)(ws + 167265552);    // 131,072
  unsigned short* W3s = (unsigned short*)(ws + 167396624);    // 131,072
  unsigned short* W4s = (unsigned short*)(ws + 167527696);    // 65,536
  unsigned short* W5s = (unsigned short*)(ws + 167593232);    // 32,768
  unsigned short* W6s = (unsigned short*)(ws + 167626000);    // 16,384
  int*   btot  = (int*)  (ws + 167642896);                    // 3,128
  int*   bptr  = (int*)  (ws + 167646032);                    // 3,132
  int*   cnt   = (int*)  (ws + 167649184);                    // 196*782*4 = 613,088
  // perm overlaps cnt: cnt's last reader is scat2_k, bcsr_k (writer of perm) runs after.
  int*   perm  = cnt;                                         // NBK*128 = 100,096 ints

  hipMemsetAsync(btot, 0, NBK*4, stream);

  // fused pre-pass (hist + wswz + f2q), then scan-based multi-split CSR build
  pre_k <<<HB+WB+QB, 256, 0, stream>>>(ei, cnt, btot, x, xq,
      W1,W2,W3,W4,W5,W6, W1s,W2s,W3s,W4s,W5s,W6s);
  bkpfx_k <<<NBK, 256, 0, stream>>>(cnt, btot, bptr);
  scat2_k <<<EBLK, 256, 0, stream>>>(ei, cnt, ebuf);
  bcsr_k  <<<NBK, 256, 0, stream>>>(ebuf, bptr, rp, dinv, col, perm);

  const int GX128 = NBK*16/4;   // W=128: 16 wave-groups/bucket, 4 waves/block = 3128
  const int GX64  = NBK*8/4;    // W=64:   8 wave-groups/bucket -> 1564
  const int NYT   = (NN + 127)/128;    // gemm row-panels (782)
  const int GY8   = (NYT + 7)/8;       // row-panels per XCD stripe (98)
  const int G256  = 8*4*GY8;           // N=256: 3136 blocks
  const int G128  = 8*2*GY8;           // N=128: 1568
  const int G64   = 8*1*GY8;           // N=64:  784

  // L1: aggregate-first at width 128 (Â x, fp8 gather), then GEMM 128->256 (+b1, relu, bf16)
  spmm8_k<128,128,true,false,false><<<dim3(GX128,1),256,0,stream>>>(xq, hA, rp, col, dinv, perm, nullptr);
  mgemm_k<128,256,0><<<G256,256,0,stream>>>(hA, W1s, b1, hB, nullptr, NN);
  // L2: GEMM (*dinv -> fp8), spmm fp8 gather split into two 128-col slices (+b2, relu -> bf16)
  mgemm_k<256,256,1><<<G256,256,0,stream>>>(hB, W2s, dinv, nullptr, hQ, NN);
  spmm8_k<256,128,false,true,true><<<dim3(GX128,2),256,0,stream>>>(hQ, hA, rp, col, dinv, perm, b2);
  // L3
  mgemm_k<256,256,1><<<G256,256,0,stream>>>(hA, W3s, dinv, nullptr, hQ, NN);
  spmm8_k<256,128,false,true,true><<<dim3(GX128,2),256,0,stream>>>(hQ, hB, rp, col, dinv, perm, b3);
  // L4: 256->128
  mgemm_k<256,128,1><<<G128,256,0,stream>>>(hB, W4s, dinv, nullptr, hQ, NN);
  spmm8_k<128,128,false,true,true><<<dim3(GX128,1),256,0,stream>>>(hQ, hA, rp, col, dinv, perm, b4);
  // L5: 128->128
  mgemm_k<128,128,1><<<G128,256,0,stream>>>(hA, W5s, dinv, nullptr, hQ, NN);
  spmm8_k<128,128,false,true,true><<<dim3(GX128,1),256,0,stream>>>(hQ, hB, rp, col, dinv, perm, b5);
  // L6: 128->64, no relu
  mgemm_k<128,64,1><<<G64,256,0,stream>>>(hB, W6s, dinv, nullptr, hQ, NN);
  spmm8_k<64,64,false,false,true><<<dim3(GX64,1),256,0,stream>>>(hQ, hA, rp, col, dinv, perm, b6);

  // fused deterministic mean-pool + head
  poolhead_k<<<NG, 256, 0, stream>>>(hA, batch, Wl, bl, out);
}